// Round 1
// 1603.897 us; speedup vs baseline: 1.0137x; 1.0137x over previous
//
#include <hip/hip_runtime.h>
#include <hip/hip_bf16.h>
#include <stdint.h>

#define N_NODES 16384
#define GG      128
#define HD      64
#define MAXD    192
#define BN_EPS  1e-5f

typedef unsigned short u16;
typedef unsigned int   u32;
typedef unsigned long long u64;
typedef u32 u32x4 __attribute__((ext_vector_type(4)));  // nontemporal-compatible

__device__ __forceinline__ float bf2f(u16 u) {
    union { u32 i; float f; } c; c.i = ((u32)u) << 16; return c.f;
}
// param load in native dtype (flag: 1=f32, 0=bf16)
__device__ __forceinline__ float ldp(const void* p, int i, int flag) {
    return flag ? ((const float*)p)[i] : bf2f(((const u16*)p)[i]);
}

// ---------------------------------------------------------------------------
// Fused scan+gather: one wave per row.
//  phase 1: streaming ballot-compaction scan of adj row -> cols in LDS
//           (NON-TEMPORAL loads, 2-deep prefetch; 1 GiB stream must not
//            evict x from L2)
//  phase 2: stream LDS cols to global (for k_spmm) + gather
//           pooled[i,:] = (1/deg_i) * sum_k x[cols[i,k],:]
// Also does the old k_init housekeeping: zero f64 stats (blocks 0-1) and
// publish the dtype flag probed from adj[0][0]==1.0
// (f32 -> word0 low16 == 0; bf16 -> low16 = 0x3F80 != 0).
__global__ __launch_bounds__(256) void k_scan_gather(
    const void* __restrict__ adjv, const void* __restrict__ xv,
    u16* __restrict__ cols, int* __restrict__ cnt,
    float* __restrict__ invdeg, float* __restrict__ pooled,
    double* __restrict__ statsD, int* __restrict__ flagp)
{
    __shared__ __align__(16) u16 sc[4][MAXD];
    const int wave = threadIdx.x >> 6, lane = threadIdx.x & 63;
    const int row = blockIdx.x * 4 + wave;
    const u32 w0 = *(const u32*)adjv;                      // scalar, cached
    const int flag = ((w0 & 0xFFFFu) == 0) ? 1 : 0;
    const u64 ltmask = ((1ull << lane) - 1ull);

    // housekeeping (replaces k_init)
    const int gid = blockIdx.x * 256 + threadIdx.x;
    if (gid < 512) statsD[gid] = 0.0;
    if (gid == 0) *flagp = flag;

    u16* __restrict__ srow = sc[wave];
    int base = 0;
    if (flag) {  // ---- f32: u32x4 = 4 elements, 256 elems/wave-chunk ----
        const u32x4* __restrict__ arow =
            (const u32x4*)((const u32*)adjv + (size_t)row * N_NODES) + lane;
        u32x4 p0 = __builtin_nontemporal_load(arow);
        u32x4 p1 = __builtin_nontemporal_load(arow + 64);
        for (int c = 0; c < N_NODES; c += 256) {
            u32x4 raw = p0;
            p0 = p1;
            if (c + 512 < N_NODES)
                p1 = __builtin_nontemporal_load(arow + (c + 512) / 4);
            #pragma unroll
            for (int e = 0; e < 4; ++e) {
                u32 w = raw[e];
                u64 m = __ballot(w != 0);
                if (m) {
                    if (w) {
                        int p = base + __popcll(m & ltmask);
                        if (p < MAXD) srow[p] = (u16)(c + lane * 4 + e);
                    }
                    base += __popcll(m);
                }
            }
        }
    } else {     // ---- bf16: u32x4 = 8 elements, 512 elems/wave-chunk ----
        const u32x4* __restrict__ arow =
            (const u32x4*)((const u16*)adjv + (size_t)row * N_NODES) + lane;
        u32x4 p0 = __builtin_nontemporal_load(arow);
        u32x4 p1 = __builtin_nontemporal_load(arow + 64);
        for (int c = 0; c < N_NODES; c += 512) {
            u32x4 raw = p0;
            p0 = p1;
            if (c + 1024 < N_NODES)
                p1 = __builtin_nontemporal_load(arow + (c + 1024) / 8);
            #pragma unroll
            for (int e = 0; e < 8; ++e) {
                u16 u = (u16)(raw[e >> 1] >> ((e & 1) * 16));
                u64 m = __ballot(u != 0);
                if (m) {
                    if (u) {
                        int p = base + __popcll(m & ltmask);
                        if (p < MAXD) srow[p] = (u16)(c + lane * 8 + e);
                    }
                    base += __popcll(m);
                }
            }
        }
    }
    const int n = (base < MAXD) ? base : MAXD;
    if (lane == 0) cnt[row] = n;
    __syncthreads();   // LDS cols visible (same-wave RAW ordering made explicit)

    // stream cols to global for k_spmm (coalesced u32 copy; garbage > n ok,
    // reads are bounded by cnt)
    {
        u32* __restrict__ crow32 = (u32*)(cols + (size_t)row * MAXD);
        const u32* __restrict__ s32 = (const u32*)srow;
        #pragma unroll
        for (int t = lane; t < MAXD / 2; t += 64) crow32[t] = s32[t];
    }

    // gather: cols read from LDS are wave-uniform broadcasts (free)
    float acc = 0.f;
    int k = 0;
    if (flag) {
        const float* __restrict__ x = (const float*)xv;
        for (; k + 4 <= n; k += 4) {
            ushort4 j4 = *(const ushort4*)&srow[k];
            float v0 = x[(size_t)j4.x * HD + lane];
            float v1 = x[(size_t)j4.y * HD + lane];
            float v2 = x[(size_t)j4.z * HD + lane];
            float v3 = x[(size_t)j4.w * HD + lane];
            acc += (v0 + v1) + (v2 + v3);
        }
        for (; k < n; ++k) acc += x[(size_t)srow[k] * HD + lane];
    } else {
        const u16* __restrict__ x = (const u16*)xv;
        for (; k + 4 <= n; k += 4) {
            ushort4 j4 = *(const ushort4*)&srow[k];
            float v0 = bf2f(x[(size_t)j4.x * HD + lane]);
            float v1 = bf2f(x[(size_t)j4.y * HD + lane]);
            float v2 = bf2f(x[(size_t)j4.z * HD + lane]);
            float v3 = bf2f(x[(size_t)j4.w * HD + lane]);
            acc += (v0 + v1) + (v2 + v3);
        }
        for (; k < n; ++k) acc += bf2f(x[(size_t)srow[k] * HD + lane]);
    }
    float inv = 1.f / (float)n;                     // n >= 1 (self-loop)
    pooled[(size_t)row * HD + lane] = acc * inv;
    if (lane == 0) invdeg[row] = inv;
}

// ---------------------------------------------------------------------------
// dst[N,64] = f(src)[N,64] @ W[64,64] + bias.
// f = identity (AFFINE=false) or per-feature relu(A*v+C) (AFFINE=true).
// 16 rows/block (1024 blocks): W-staging amortized 4x vs the old 4-row
// version; each thread owns 4 rows of one output feature.
// S-reads are wave-uniform broadcasts; Wf reads stride-1 (2-way, free).
template<bool AFFINE>
__global__ __launch_bounds__(256) void k_mm(
    const float* __restrict__ src, const double* __restrict__ stats,
    const void* __restrict__ g, const void* __restrict__ be,
    const void* __restrict__ W, const void* __restrict__ bias,
    float* __restrict__ dst, const int* __restrict__ flagp)
{
    __shared__ float Wf[64 * 64];
    __shared__ float S[16 * 64];
    __shared__ float ac[128];
    const int tid = threadIdx.x;
    const int flag = *flagp;
    if (AFFINE) {
        if (tid < 64) {
            double m = stats[tid] * (1.0 / N_NODES);
            double v = stats[64 + tid] * (1.0 / N_NODES) - m * m;
            float A = ldp(g, tid, flag) / sqrtf((float)v + BN_EPS);
            ac[tid] = A;
            ac[64 + tid] = ldp(be, tid, flag) - (float)m * A;
        }
        __syncthreads();
    }
    for (int i = tid; i < 64 * 64; i += 256) Wf[i] = ldp(W, i, flag);
    const int rbase = blockIdx.x * 16;
    {
        float4 v = *(const float4*)&src[(size_t)rbase * 64 + tid * 4];
        if (AFFINE) {
            const int f0 = (tid * 4) & 63;
            v.x = fmaxf(fmaf(ac[f0 + 0], v.x, ac[64 + f0 + 0]), 0.f);
            v.y = fmaxf(fmaf(ac[f0 + 1], v.y, ac[64 + f0 + 1]), 0.f);
            v.z = fmaxf(fmaf(ac[f0 + 2], v.z, ac[64 + f0 + 2]), 0.f);
            v.w = fmaxf(fmaf(ac[f0 + 3], v.w, ac[64 + f0 + 3]), 0.f);
        }
        *(float4*)&S[tid * 4] = v;
    }
    __syncthreads();
    const int f = tid & 63, r0 = (tid >> 6) * 4;
    const float b = ldp(bias, f, flag);
    float a0 = b, a1 = b, a2 = b, a3 = b;
    #pragma unroll
    for (int k = 0; k < 64; ++k) {
        const float wk = Wf[k * 64 + f];
        a0 = fmaf(S[(r0 + 0) * 64 + k], wk, a0);
        a1 = fmaf(S[(r0 + 1) * 64 + k], wk, a1);
        a2 = fmaf(S[(r0 + 2) * 64 + k], wk, a2);
        a3 = fmaf(S[(r0 + 3) * 64 + k], wk, a3);
    }
    dst[(size_t)(rbase + r0 + 0) * 64 + f] = a0;
    dst[(size_t)(rbase + r0 + 1) * 64 + f] = a1;
    dst[(size_t)(rbase + r0 + 2) * 64 + f] = a2;
    dst[(size_t)(rbase + r0 + 3) * 64 + f] = a3;
}

// ---------------------------------------------------------------------------
// Column stats in f64: statsOut[f] += sum, statsOut[64+f] += sumsq.
// 256 blocks -> 256 serial RMWs/address (proven cheap; do NOT widen grid).
__global__ __launch_bounds__(256) void k_stats(
    const float* __restrict__ src, double* __restrict__ statsOut)
{
    __shared__ double shs[256];
    __shared__ double shq[256];
    const int tid = threadIdx.x;
    const int f = tid & 63, rsub = tid >> 6;
    const int rbase = blockIdx.x * 64;
    double s = 0.0, q = 0.0;
    for (int r = rsub; r < 64; r += 4) {
        float v = src[(size_t)(rbase + r) * 64 + f];
        s += (double)v;
        q += (double)v * (double)v;
    }
    shs[tid] = s; shq[tid] = q;
    __syncthreads();
    if (tid < 64) {
        double S = shs[tid] + shs[64 + tid] + shs[128 + tid] + shs[192 + tid];
        double Q = shq[tid] + shq[64 + tid] + shq[128 + tid] + shq[192 + tid];
        atomicAdd(&statsOut[tid], S);
        atomicAdd(&statsOut[64 + tid], Q);
    }
}

// ---------------------------------------------------------------------------
// dst = relu(A*src + C) (final h1 -> output 1)
__global__ __launch_bounds__(256) void k_bnrelu(
    const float* __restrict__ src, const double* __restrict__ stats,
    const void* __restrict__ g, const void* __restrict__ be,
    float* __restrict__ dst, const int* __restrict__ flagp)
{
    __shared__ float ac[128];
    const int tid = threadIdx.x;
    const int flag = *flagp;
    if (tid < 64) {
        double m = stats[tid] * (1.0 / N_NODES);
        double v = stats[64 + tid] * (1.0 / N_NODES) - m * m;
        float A = ldp(g, tid, flag) / sqrtf((float)v + BN_EPS);
        ac[tid] = A;
        ac[64 + tid] = ldp(be, tid, flag) - (float)m * A;
    }
    __syncthreads();
    const size_t idx = ((size_t)blockIdx.x * 256 + tid) * 4;
    const int f0 = (int)(idx & 63);
    float4 t = *(const float4*)&src[idx];
    const float4 A4 = *(const float4*)&ac[f0];
    const float4 C4 = *(const float4*)&ac[64 + f0];
    float4 r;
    r.x = fmaxf(fmaf(A4.x, t.x, C4.x), 0.f);
    r.y = fmaxf(fmaf(A4.y, t.y, C4.y), 0.f);
    r.z = fmaxf(fmaf(A4.z, t.z, C4.z), 0.f);
    r.w = fmaxf(fmaf(A4.w, t.w, C4.w), 0.f);
    *(float4*)&dst[idx] = r;
}

// ---------------------------------------------------------------------------
// pooled[i,:] = invdeg[i] * sum_k relu(A*t[cols[i,k],:]+C)
// (layer-0 outer BN+relu fused into the layer-1 aggregation gather)
__global__ __launch_bounds__(256) void k_spmm(
    const float* __restrict__ t, const double* __restrict__ stats,
    const void* __restrict__ g, const void* __restrict__ be,
    const u16* __restrict__ cols, const int* __restrict__ cnt,
    const float* __restrict__ invdeg, float* __restrict__ pooled,
    const int* __restrict__ flagp)
{
    const int wave = threadIdx.x >> 6, lane = threadIdx.x & 63;
    const int row = blockIdx.x * 4 + wave;
    const int flag = *flagp;
    double md = stats[lane] * (1.0 / N_NODES);
    double vd = stats[64 + lane] * (1.0 / N_NODES) - md * md;
    const float A = ldp(g, lane, flag) / sqrtf((float)vd + BN_EPS);
    const float C = ldp(be, lane, flag) - (float)md * A;

    const u16* __restrict__ crow = cols + (size_t)row * MAXD;
    const int n = cnt[row];
    float acc = 0.f;
    int k = 0;
    for (; k + 4 <= n; k += 4) {
        ushort4 j4 = *(const ushort4*)&crow[k];
        float v0 = t[(size_t)j4.x * HD + lane];
        float v1 = t[(size_t)j4.y * HD + lane];
        float v2 = t[(size_t)j4.z * HD + lane];
        float v3 = t[(size_t)j4.w * HD + lane];
        acc += fmaxf(fmaf(A, v0, C), 0.f);
        acc += fmaxf(fmaf(A, v1, C), 0.f);
        acc += fmaxf(fmaf(A, v2, C), 0.f);
        acc += fmaxf(fmaf(A, v3, C), 0.f);
    }
    for (; k < n; ++k) {
        float vv = t[(size_t)crow[k] * HD + lane];
        acc += fmaxf(fmaf(A, vv, C), 0.f);
    }
    pooled[(size_t)row * HD + lane] = acc * invdeg[row];
}

// ---------------------------------------------------------------------------
// out[g,:] = sum_j gp[g,j] * h[j,:]; zero weights skipped (wave-uniform test)
__global__ __launch_bounds__(1024) void k_pool(
    const void* __restrict__ gpv, const float* __restrict__ h,
    float* __restrict__ out, const int* __restrict__ flagp)
{
    __shared__ float red[16 * 64];
    const int g = blockIdx.x;
    const int wave = threadIdx.x >> 6, lane = threadIdx.x & 63;
    const int flag = *flagp;
    float acc = 0.f;
    const int jb0 = wave * (N_NODES / 16);
    if (flag) {
        const float* __restrict__ grow = (const float*)gpv + (size_t)g * N_NODES;
        for (int jb = jb0; jb < jb0 + N_NODES / 16; jb += 4) {
            float4 raw = *(const float4*)(grow + jb);
            if (raw.x != 0.f) acc += raw.x * h[(size_t)(jb + 0) * HD + lane];
            if (raw.y != 0.f) acc += raw.y * h[(size_t)(jb + 1) * HD + lane];
            if (raw.z != 0.f) acc += raw.z * h[(size_t)(jb + 2) * HD + lane];
            if (raw.w != 0.f) acc += raw.w * h[(size_t)(jb + 3) * HD + lane];
        }
    } else {
        const u16* __restrict__ grow = (const u16*)gpv + (size_t)g * N_NODES;
        for (int jb = jb0; jb < jb0 + N_NODES / 16; jb += 8) {
            uint4 raw = *(const uint4*)(grow + jb);
            const u32 w[4] = {raw.x, raw.y, raw.z, raw.w};
            #pragma unroll
            for (int e = 0; e < 8; ++e) {
                u16 u = (u16)(w[e >> 1] >> ((e & 1) * 16));
                if (u) acc += bf2f(u) * h[(size_t)(jb + e) * HD + lane];
            }
        }
    }
    red[wave * 64 + lane] = acc;
    __syncthreads();
    if (wave == 0) {
        float s = 0.f;
        #pragma unroll
        for (int w2 = 0; w2 < 16; ++w2) s += red[w2 * 64 + lane];
        out[g * 64 + lane] = s;
    }
}

// ---------------------------------------------------------------------------
extern "C" void kernel_launch(void* const* d_in, const int* in_sizes, int n_in,
                              void* d_out, int out_size, void* d_ws, size_t ws_size,
                              hipStream_t stream)
{
    const void* x    = d_in[0];
    const void* adj  = d_in[1];
    const void* gp   = d_in[2];
    const void* W1_0 = d_in[3];
    const void* b1_0 = d_in[4];
    const void* g1_0 = d_in[5];
    const void* be1_0= d_in[6];
    const void* W2_0 = d_in[7];
    const void* b2_0 = d_in[8];
    const void* g_0  = d_in[9];
    const void* be_0 = d_in[10];
    const void* W1_1 = d_in[11];
    const void* b1_1 = d_in[12];
    const void* g1_1 = d_in[13];
    const void* be1_1= d_in[14];
    const void* W2_1 = d_in[15];
    const void* b2_1 = d_in[16];
    const void* g_1  = d_in[17];
    const void* be_1 = d_in[18];

    char* ws = (char*)d_ws;
    float*  P      = (float*) (ws);                        // 4 MB
    float*  A      = (float*) (ws + (4u  << 20));          // 4 MB
    float*  B      = (float*) (ws + (8u  << 20));          // 4 MB
    u16*    cols   = (u16*)   (ws + (12u << 20));          // 6 MB
    int*    cnt    = (int*)   (ws + (18u << 20));          // 64 KB
    float*  invdeg = (float*) (ws + (18u << 20) + 65536);  // 64 KB
    double* sd     = (double*)(ws + (18u << 20) + 131072); // 512 f64
    int*    flag   = (int*)   (ws + (18u << 20) + 131072 + 4096);

    // Outputs are float32. Output 1 (h_nodes) written by final k_bnrelu;
    // k_pool reads it from d_out.
    float* out_pool  = (float*)d_out;            // [128,64]
    float* out_nodes = (float*)d_out + GG * HD;  // [16384,64]

    const int EB = (N_NODES * HD / 4) / 256;  // elementwise grid (1024)

    k_scan_gather<<<N_NODES / 4, 256, 0, stream>>>(adj, x, cols, cnt,
                                                   invdeg, P, sd, flag);

    // ----- layer 0 -----
    k_mm<false><<<N_NODES / 16, 256, 0, stream>>>(P, nullptr, nullptr, nullptr,
                                                  W1_0, b1_0, A, flag);
    k_stats<<<256, 256, 0, stream>>>(A, sd + 0);
    k_mm<true><<<N_NODES / 16, 256, 0, stream>>>(A, sd + 0, g1_0, be1_0,
                                                 W2_0, b2_0, P, flag);
    k_stats<<<256, 256, 0, stream>>>(P, sd + 128);
    // layer-0 outer BN+relu fused into the layer-1 aggregation gather:
    k_spmm<<<N_NODES / 4, 256, 0, stream>>>(P, sd + 128, g_0, be_0,
                                            cols, cnt, invdeg, B, flag);
    // ----- layer 1 -----
    k_mm<false><<<N_NODES / 16, 256, 0, stream>>>(B, nullptr, nullptr, nullptr,
                                                  W1_1, b1_1, A, flag);
    k_stats<<<256, 256, 0, stream>>>(A, sd + 256);
    k_mm<true><<<N_NODES / 16, 256, 0, stream>>>(A, sd + 256, g1_1, be1_1,
                                                 W2_1, b2_1, P, flag);
    k_stats<<<256, 256, 0, stream>>>(P, sd + 384);
    k_bnrelu<<<EB, 256, 0, stream>>>(P, sd + 384, g_1, be_1, out_nodes, flag);
    k_pool<<<GG, 1024, 0, stream>>>(gp, out_nodes, out_pool, flag);
}

// Round 2
// 1543.945 us; speedup vs baseline: 1.0531x; 1.0388x over previous
//
#include <hip/hip_runtime.h>
#include <hip/hip_bf16.h>
#include <stdint.h>

#define N_NODES 16384
#define GG      128
#define HD      64
#define MAXD    192
#define BN_EPS  1e-5f
#define NSLOT   16   // stats contention slots (64 serialized RMWs/address)

typedef unsigned short u16;
typedef unsigned int   u32;
typedef unsigned long long u64;
typedef u32 u32x4 __attribute__((ext_vector_type(4)));  // nontemporal-compatible

__device__ __forceinline__ float bf2f(u16 u) {
    union { u32 i; float f; } c; c.i = ((u32)u) << 16; return c.f;
}
// param load in native dtype (flag: 1=f32, 0=bf16)
__device__ __forceinline__ float ldp(const void* p, int i, int flag) {
    return flag ? ((const float*)p)[i] : bf2f(((const u16*)p)[i]);
}

// ---------------------------------------------------------------------------
// Fused scan+gather: one wave per row.
//  phase 1: streaming ballot-compaction scan of adj row -> cols in LDS
//           (NON-TEMPORAL loads, 2-deep prefetch; the big stream must not
//            evict x from L2)
//  phase 2: stream LDS cols to global (for k_spmm) + gather
//           pooled[i,:] = (1/deg_i) * sum_k x[cols[i,k],:]
// Housekeeping: zero the 8192-double stats arena, publish dtype flag probed
// from adj[0][0]==1.0 (f32 -> word0 low16 == 0; bf16 -> low16 = 0x3F80).
__global__ __launch_bounds__(256) void k_scan_gather(
    const void* __restrict__ adjv, const void* __restrict__ xv,
    u16* __restrict__ cols, int* __restrict__ cnt,
    float* __restrict__ invdeg, float* __restrict__ pooled,
    double* __restrict__ statsD, int* __restrict__ flagp)
{
    __shared__ __align__(16) u16 sc[4][MAXD];
    const int wave = threadIdx.x >> 6, lane = threadIdx.x & 63;
    const int row = blockIdx.x * 4 + wave;
    const u32 w0 = *(const u32*)adjv;                      // scalar, cached
    const int flag = ((w0 & 0xFFFFu) == 0) ? 1 : 0;
    const u64 ltmask = ((1ull << lane) - 1ull);

    // housekeeping
    const int gid = blockIdx.x * 256 + threadIdx.x;
    if (gid < 4 * NSLOT * 128) statsD[gid] = 0.0;
    if (gid == 0) *flagp = flag;

    u16* __restrict__ srow = sc[wave];
    int base = 0;
    if (flag) {  // ---- f32: u32x4 = 4 elements, 256 elems/wave-chunk ----
        const u32x4* __restrict__ arow =
            (const u32x4*)((const u32*)adjv + (size_t)row * N_NODES) + lane;
        u32x4 p0 = __builtin_nontemporal_load(arow);
        u32x4 p1 = __builtin_nontemporal_load(arow + 64);
        for (int c = 0; c < N_NODES; c += 256) {
            u32x4 raw = p0;
            p0 = p1;
            if (c + 512 < N_NODES)
                p1 = __builtin_nontemporal_load(arow + (c + 512) / 4);
            #pragma unroll
            for (int e = 0; e < 4; ++e) {
                u32 w = raw[e];
                u64 m = __ballot(w != 0);
                if (m) {
                    if (w) {
                        int p = base + __popcll(m & ltmask);
                        if (p < MAXD) srow[p] = (u16)(c + lane * 4 + e);
                    }
                    base += __popcll(m);
                }
            }
        }
    } else {     // ---- bf16: u32x4 = 8 elements, 512 elems/wave-chunk ----
        const u32x4* __restrict__ arow =
            (const u32x4*)((const u16*)adjv + (size_t)row * N_NODES) + lane;
        u32x4 p0 = __builtin_nontemporal_load(arow);
        u32x4 p1 = __builtin_nontemporal_load(arow + 64);
        for (int c = 0; c < N_NODES; c += 512) {
            u32x4 raw = p0;
            p0 = p1;
            if (c + 1024 < N_NODES)
                p1 = __builtin_nontemporal_load(arow + (c + 1024) / 8);
            #pragma unroll
            for (int e = 0; e < 8; ++e) {
                u16 u = (u16)(raw[e >> 1] >> ((e & 1) * 16));
                u64 m = __ballot(u != 0);
                if (m) {
                    if (u) {
                        int p = base + __popcll(m & ltmask);
                        if (p < MAXD) srow[p] = (u16)(c + lane * 8 + e);
                    }
                    base += __popcll(m);
                }
            }
        }
    }
    const int n = (base < MAXD) ? base : MAXD;
    if (lane == 0) cnt[row] = n;
    __syncthreads();   // LDS cols visible

    // stream cols to global for k_spmm (coalesced u32 copy; garbage > n ok,
    // reads are bounded by cnt)
    {
        u32* __restrict__ crow32 = (u32*)(cols + (size_t)row * MAXD);
        const u32* __restrict__ s32 = (const u32*)srow;
        #pragma unroll
        for (int t = lane; t < MAXD / 2; t += 64) crow32[t] = s32[t];
    }

    // gather: cols read from LDS are wave-uniform broadcasts (free)
    float acc = 0.f;
    int k = 0;
    if (flag) {
        const float* __restrict__ x = (const float*)xv;
        for (; k + 4 <= n; k += 4) {
            ushort4 j4 = *(const ushort4*)&srow[k];
            float v0 = x[(size_t)j4.x * HD + lane];
            float v1 = x[(size_t)j4.y * HD + lane];
            float v2 = x[(size_t)j4.z * HD + lane];
            float v3 = x[(size_t)j4.w * HD + lane];
            acc += (v0 + v1) + (v2 + v3);
        }
        for (; k < n; ++k) acc += x[(size_t)srow[k] * HD + lane];
    } else {
        const u16* __restrict__ x = (const u16*)xv;
        for (; k + 4 <= n; k += 4) {
            ushort4 j4 = *(const ushort4*)&srow[k];
            float v0 = bf2f(x[(size_t)j4.x * HD + lane]);
            float v1 = bf2f(x[(size_t)j4.y * HD + lane]);
            float v2 = bf2f(x[(size_t)j4.z * HD + lane]);
            float v3 = bf2f(x[(size_t)j4.w * HD + lane]);
            acc += (v0 + v1) + (v2 + v3);
        }
        for (; k < n; ++k) acc += bf2f(x[(size_t)srow[k] * HD + lane]);
    }
    float inv = 1.f / (float)n;                     // n >= 1 (self-loop)
    pooled[(size_t)row * HD + lane] = acc * inv;
    if (lane == 0) invdeg[row] = inv;
}

// ---------------------------------------------------------------------------
// dst[N,64] = f(src)[N,64] @ W[64,64] + bias, PLUS fused column stats of dst:
// statsOut[slot*128 + f] += sum, statsOut[slot*128 + 64 + f] += sumsq, where
// slot = blockIdx & 15 (64 serialized f64 RMWs/address — cheap).
// f = identity (AFFINE=false) or per-feature relu(A*v+C) (AFFINE=true) with
// A,C derived from the 16-slot statsIn arena.
// 16 rows/block (1024 blocks); each thread owns 4 rows of one output feature.
template<bool AFFINE>
__global__ __launch_bounds__(256) void k_mm(
    const float* __restrict__ src, const double* __restrict__ statsIn,
    const void* __restrict__ g, const void* __restrict__ be,
    const void* __restrict__ W, const void* __restrict__ bias,
    float* __restrict__ dst, double* __restrict__ statsOut,
    const int* __restrict__ flagp)
{
    __shared__ float Wf[64 * 64];
    __shared__ float S[16 * 64];
    __shared__ float ac[128];
    __shared__ double shs[256];
    __shared__ double shq[256];
    const int tid = threadIdx.x;
    const int flag = *flagp;
    if (AFFINE) {
        if (tid < 64) {
            double ss = 0.0, qq = 0.0;
            #pragma unroll
            for (int s2 = 0; s2 < NSLOT; ++s2) {
                ss += statsIn[s2 * 128 + tid];
                qq += statsIn[s2 * 128 + 64 + tid];
            }
            double m = ss * (1.0 / N_NODES);
            double v = qq * (1.0 / N_NODES) - m * m;
            float A = ldp(g, tid, flag) / sqrtf((float)v + BN_EPS);
            ac[tid] = A;
            ac[64 + tid] = ldp(be, tid, flag) - (float)m * A;
        }
        __syncthreads();
    }
    for (int i = tid; i < 64 * 64; i += 256) Wf[i] = ldp(W, i, flag);
    const int rbase = blockIdx.x * 16;
    {
        float4 v = *(const float4*)&src[(size_t)rbase * 64 + tid * 4];
        if (AFFINE) {
            const int f0 = (tid * 4) & 63;
            v.x = fmaxf(fmaf(ac[f0 + 0], v.x, ac[64 + f0 + 0]), 0.f);
            v.y = fmaxf(fmaf(ac[f0 + 1], v.y, ac[64 + f0 + 1]), 0.f);
            v.z = fmaxf(fmaf(ac[f0 + 2], v.z, ac[64 + f0 + 2]), 0.f);
            v.w = fmaxf(fmaf(ac[f0 + 3], v.w, ac[64 + f0 + 3]), 0.f);
        }
        *(float4*)&S[tid * 4] = v;
    }
    __syncthreads();
    const int f = tid & 63, r0 = (tid >> 6) * 4;
    const float b = ldp(bias, f, flag);
    float a0 = b, a1 = b, a2 = b, a3 = b;
    #pragma unroll
    for (int k = 0; k < 64; ++k) {
        const float wk = Wf[k * 64 + f];
        a0 = fmaf(S[(r0 + 0) * 64 + k], wk, a0);
        a1 = fmaf(S[(r0 + 1) * 64 + k], wk, a1);
        a2 = fmaf(S[(r0 + 2) * 64 + k], wk, a2);
        a3 = fmaf(S[(r0 + 3) * 64 + k], wk, a3);
    }
    dst[(size_t)(rbase + r0 + 0) * 64 + f] = a0;
    dst[(size_t)(rbase + r0 + 1) * 64 + f] = a1;
    dst[(size_t)(rbase + r0 + 2) * 64 + f] = a2;
    dst[(size_t)(rbase + r0 + 3) * 64 + f] = a3;

    // fused column stats of this block's 16x64 tile (distinct LDS arrays;
    // no barrier needed before the writes)
    shs[tid] = (double)a0 + (double)a1 + (double)a2 + (double)a3;
    shq[tid] = (double)a0 * a0 + (double)a1 * a1
             + (double)a2 * a2 + (double)a3 * a3;
    __syncthreads();
    if (tid < 64) {
        double S2 = shs[tid] + shs[64 + tid] + shs[128 + tid] + shs[192 + tid];
        double Q2 = shq[tid] + shq[64 + tid] + shq[128 + tid] + shq[192 + tid];
        double* so = statsOut + (blockIdx.x & (NSLOT - 1)) * 128;
        atomicAdd(&so[tid], S2);
        atomicAdd(&so[64 + tid], Q2);
    }
}

// ---------------------------------------------------------------------------
// pooled[i,:] = invdeg[i] * sum_k relu(A*t[cols[i,k],:]+C)
// (layer-0 outer BN+relu fused into the layer-1 aggregation gather;
//  A,C computed once per block from the 16-slot stats arena)
__global__ __launch_bounds__(256) void k_spmm(
    const float* __restrict__ t, const double* __restrict__ statsIn,
    const void* __restrict__ g, const void* __restrict__ be,
    const u16* __restrict__ cols, const int* __restrict__ cnt,
    const float* __restrict__ invdeg, float* __restrict__ pooled,
    const int* __restrict__ flagp)
{
    __shared__ float ac[128];
    const int tid = threadIdx.x;
    const int wave = tid >> 6, lane = tid & 63;
    const int row = blockIdx.x * 4 + wave;
    const int flag = *flagp;
    if (tid < 64) {
        double ss = 0.0, qq = 0.0;
        #pragma unroll
        for (int s2 = 0; s2 < NSLOT; ++s2) {
            ss += statsIn[s2 * 128 + tid];
            qq += statsIn[s2 * 128 + 64 + tid];
        }
        double m = ss * (1.0 / N_NODES);
        double v = qq * (1.0 / N_NODES) - m * m;
        float A = ldp(g, tid, flag) / sqrtf((float)v + BN_EPS);
        ac[tid] = A;
        ac[64 + tid] = ldp(be, tid, flag) - (float)m * A;
    }
    __syncthreads();
    const float A = ac[lane], C = ac[64 + lane];

    const u16* __restrict__ crow = cols + (size_t)row * MAXD;
    const int n = cnt[row];
    float acc = 0.f;
    int k = 0;
    for (; k + 4 <= n; k += 4) {
        ushort4 j4 = *(const ushort4*)&crow[k];
        float v0 = t[(size_t)j4.x * HD + lane];
        float v1 = t[(size_t)j4.y * HD + lane];
        float v2 = t[(size_t)j4.z * HD + lane];
        float v3 = t[(size_t)j4.w * HD + lane];
        acc += fmaxf(fmaf(A, v0, C), 0.f);
        acc += fmaxf(fmaf(A, v1, C), 0.f);
        acc += fmaxf(fmaf(A, v2, C), 0.f);
        acc += fmaxf(fmaf(A, v3, C), 0.f);
    }
    for (; k < n; ++k) {
        float vv = t[(size_t)crow[k] * HD + lane];
        acc += fmaxf(fmaf(A, vv, C), 0.f);
    }
    pooled[(size_t)row * HD + lane] = acc * invdeg[row];
}

// ---------------------------------------------------------------------------
// Fused final BN+relu AND graph pooling (two block roles, one launch).
// Blocks [0,256):   out_nodes = relu(A*P + C)   (elementwise, float4)
// Blocks [256,384): out_pool[g,:] = sum_j gp[g,j] * relu(A*P[j,:]+C)
//   (pool reads P directly + applies the affine on the fly, so it has NO
//    dependency on the bnrelu blocks; zero weights skipped)
__global__ __launch_bounds__(1024) void k_bnrelu_pool(
    const float* __restrict__ P, const double* __restrict__ statsIn,
    const void* __restrict__ g, const void* __restrict__ be,
    const void* __restrict__ gpv, float* __restrict__ out_nodes,
    float* __restrict__ out_pool, const int* __restrict__ flagp)
{
    __shared__ float ac[128];
    __shared__ float red[16 * 64];
    const int tid = threadIdx.x;
    const int flag = *flagp;
    if (tid < 64) {
        double ss = 0.0, qq = 0.0;
        #pragma unroll
        for (int s2 = 0; s2 < NSLOT; ++s2) {
            ss += statsIn[s2 * 128 + tid];
            qq += statsIn[s2 * 128 + 64 + tid];
        }
        double m = ss * (1.0 / N_NODES);
        double v = qq * (1.0 / N_NODES) - m * m;
        float A = ldp(g, tid, flag) / sqrtf((float)v + BN_EPS);
        ac[tid] = A;
        ac[64 + tid] = ldp(be, tid, flag) - (float)m * A;
    }
    __syncthreads();

    if (blockIdx.x < 256) {
        // ---- bnrelu role: 256 blocks x 1024 thr x 4 elts = N*HD ----
        const size_t idx = ((size_t)blockIdx.x * 1024 + tid) * 4;
        const int f0 = (int)(idx & 63);
        float4 t = *(const float4*)&P[idx];
        const float4 A4 = *(const float4*)&ac[f0];
        const float4 C4 = *(const float4*)&ac[64 + f0];
        float4 r;
        r.x = fmaxf(fmaf(A4.x, t.x, C4.x), 0.f);
        r.y = fmaxf(fmaf(A4.y, t.y, C4.y), 0.f);
        r.z = fmaxf(fmaf(A4.z, t.z, C4.z), 0.f);
        r.w = fmaxf(fmaf(A4.w, t.w, C4.w), 0.f);
        *(float4*)&out_nodes[idx] = r;
    } else {
        // ---- pool role: one block per graph, 16 waves ----
        const int gidx = blockIdx.x - 256;
        const int wave = tid >> 6, lane = tid & 63;
        const float A = ac[lane], C = ac[64 + lane];
        float acc = 0.f;
        const int jb0 = wave * (N_NODES / 16);
        if (flag) {
            const float* __restrict__ grow =
                (const float*)gpv + (size_t)gidx * N_NODES;
            for (int jb = jb0; jb < jb0 + N_NODES / 16; jb += 4) {
                float4 raw = *(const float4*)(grow + jb);
                if (raw.x != 0.f)
                    acc += raw.x * fmaxf(fmaf(A, P[(size_t)(jb + 0) * HD + lane], C), 0.f);
                if (raw.y != 0.f)
                    acc += raw.y * fmaxf(fmaf(A, P[(size_t)(jb + 1) * HD + lane], C), 0.f);
                if (raw.z != 0.f)
                    acc += raw.z * fmaxf(fmaf(A, P[(size_t)(jb + 2) * HD + lane], C), 0.f);
                if (raw.w != 0.f)
                    acc += raw.w * fmaxf(fmaf(A, P[(size_t)(jb + 3) * HD + lane], C), 0.f);
            }
        } else {
            const u16* __restrict__ grow =
                (const u16*)gpv + (size_t)gidx * N_NODES;
            for (int jb = jb0; jb < jb0 + N_NODES / 16; jb += 8) {
                uint4 raw = *(const uint4*)(grow + jb);
                const u32 w[4] = {raw.x, raw.y, raw.z, raw.w};
                #pragma unroll
                for (int e = 0; e < 8; ++e) {
                    u16 u = (u16)(w[e >> 1] >> ((e & 1) * 16));
                    if (u)
                        acc += bf2f(u) * fmaxf(fmaf(A, P[(size_t)(jb + e) * HD + lane], C), 0.f);
                }
            }
        }
        red[wave * 64 + lane] = acc;
        __syncthreads();
        if (wave == 0) {
            float s = 0.f;
            #pragma unroll
            for (int w2 = 0; w2 < 16; ++w2) s += red[w2 * 64 + lane];
            out_pool[gidx * 64 + lane] = s;
        }
    }
}

// ---------------------------------------------------------------------------
extern "C" void kernel_launch(void* const* d_in, const int* in_sizes, int n_in,
                              void* d_out, int out_size, void* d_ws, size_t ws_size,
                              hipStream_t stream)
{
    const void* x    = d_in[0];
    const void* adj  = d_in[1];
    const void* gp   = d_in[2];
    const void* W1_0 = d_in[3];
    const void* b1_0 = d_in[4];
    const void* g1_0 = d_in[5];
    const void* be1_0= d_in[6];
    const void* W2_0 = d_in[7];
    const void* b2_0 = d_in[8];
    const void* g_0  = d_in[9];
    const void* be_0 = d_in[10];
    const void* W1_1 = d_in[11];
    const void* b1_1 = d_in[12];
    const void* g1_1 = d_in[13];
    const void* be1_1= d_in[14];
    const void* W2_1 = d_in[15];
    const void* b2_1 = d_in[16];
    const void* g_1  = d_in[17];
    const void* be_1 = d_in[18];

    char* ws = (char*)d_ws;
    float*  P      = (float*) (ws);                        // 4 MB
    float*  A      = (float*) (ws + (4u  << 20));          // 4 MB
    float*  B      = (float*) (ws + (8u  << 20));          // 4 MB
    u16*    cols   = (u16*)   (ws + (12u << 20));          // 6 MB
    int*    cnt    = (int*)   (ws + (18u << 20));          // 64 KB
    float*  invdeg = (float*) (ws + (18u << 20) + 65536);  // 64 KB
    double* sd     = (double*)(ws + (18u << 20) + 131072); // 8192 f64 (64 KB)
    int*    flag   = (int*)   (ws + (18u << 20) + 131072 + 65536);

    // Outputs are float32.
    float* out_pool  = (float*)d_out;            // [128,64]
    float* out_nodes = (float*)d_out + GG * HD;  // [16384,64]

    // stats arena: 4 groups x NSLOT(16) slots x 128 doubles
    double* st0 = sd + 0 * NSLOT * 128;   // stats(A)  layer 0
    double* st1 = sd + 1 * NSLOT * 128;   // stats(P)  layer 0
    double* st2 = sd + 2 * NSLOT * 128;   // stats(A)  layer 1
    double* st3 = sd + 3 * NSLOT * 128;   // stats(P)  layer 1

    k_scan_gather<<<N_NODES / 4, 256, 0, stream>>>(adj, x, cols, cnt,
                                                   invdeg, P, sd, flag);

    // ----- layer 0 -----
    k_mm<false><<<N_NODES / 16, 256, 0, stream>>>(P, nullptr, nullptr, nullptr,
                                                  W1_0, b1_0, A, st0, flag);
    k_mm<true><<<N_NODES / 16, 256, 0, stream>>>(A, st0, g1_0, be1_0,
                                                 W2_0, b2_0, P, st1, flag);
    // layer-0 outer BN+relu fused into the layer-1 aggregation gather:
    k_spmm<<<N_NODES / 4, 256, 0, stream>>>(P, st1, g_0, be_0,
                                            cols, cnt, invdeg, B, flag);
    // ----- layer 1 -----
    k_mm<false><<<N_NODES / 16, 256, 0, stream>>>(B, nullptr, nullptr, nullptr,
                                                  W1_1, b1_1, A, st2, flag);
    k_mm<true><<<N_NODES / 16, 256, 0, stream>>>(A, st2, g1_1, be1_1,
                                                 W2_1, b2_1, P, st3, flag);
    // final BN+relu (-> out_nodes) and graph pooling (-> out_pool), fused:
    k_bnrelu_pool<<<256 + GG, 1024, 0, stream>>>(P, st3, g_1, be_1, gp,
                                                 out_nodes, out_pool, flag);
}